// Round 5
// baseline (4949.786 us; speedup 1.0000x reference)
//
#include <hip/hip_runtime.h>
#include <hip/hip_bf16.h>

// Problem constants
#define SEQL 4096
#define VECT 300
#define DP   320     // padded feature dim (k-dim), 10 chunks of 32
#define NQT  20      // n-tiles (320 cols) for projection GEMMs
#define HN   128
#define G3   384     // 3*H
#define JC   4       // flash j-chunks (split-K over key dim)

typedef unsigned short u16;
typedef __attribute__((ext_vector_type(8))) short bf16x8;  // 8 bf16 = 4 VGPRs
typedef __attribute__((ext_vector_type(4))) float f32x4;

#define MFMA(a,b,c) __builtin_amdgcn_mfma_f32_16x16x32_bf16(a,b,c,0,0,0)
// Verified layouts (learn_hip m89/m91/m120):
//   A[m][k]: m=lane&15, k=(lane>>4)*8+j
//   B[k][n]: n=lane&15, k=(lane>>4)*8+j
//   C/D[row][col]: col=lane&15, row=(lane>>4)*4+reg

#define L2E 1.44269504088896f

__device__ __forceinline__ float bf2f(u16 v){
    union { unsigned u; float f; } t; t.u = ((unsigned)v) << 16; return t.f;
}
__device__ __forceinline__ u16 f2bf(float f){
    union { float f; unsigned u; } t; t.f = f;
    return (u16)((t.u + 0x7FFFu + ((t.u >> 16) & 1u)) >> 16);
}
__device__ __forceinline__ float sigm_f(float x){
    return __builtin_amdgcn_rcpf(1.f + __builtin_amdgcn_exp2f(-L2E * x));
}
__device__ __forceinline__ float tanh_f(float x){
    return fmaf(2.f, __builtin_amdgcn_rcpf(1.f + __builtin_amdgcn_exp2f(-2.f * L2E * x)), -1.f);
}

// ---------------- fp32 [R][C] -> bf16 padded [Rp][Cp], optional scale
__global__ __launch_bounds__(256) void cvt_pad(const float* __restrict__ src,
                                               u16* __restrict__ dst,
                                               int R, int C, int Rp, int Cp, float scale)
{
    int n = Rp * Cp;
    for (int i = blockIdx.x * blockDim.x + threadIdx.x; i < n; i += gridDim.x * blockDim.x){
        int r = i / Cp, c = i - r * Cp;
        float v = (r < R && c < C) ? src[r * C + c] * scale : 0.f;
        dst[i] = f2bf(v);
    }
}

// ---------------- fp32 vector scale-copy
__global__ __launch_bounds__(256) void scale_copy(const float* __restrict__ src,
                                                  float* __restrict__ dst, int n, float scale)
{
    int i = blockIdx.x * blockDim.x + threadIdx.x;
    if (i < n) dst[i] = src[i] * scale;
}

// ---------------- x: fp32 [S][300] -> XF fp32 [S][320] + CUR bf16 [S][320]
__global__ __launch_bounds__(256) void pad_x(const float* __restrict__ src,
                                             float* __restrict__ xf, u16* __restrict__ cur)
{
    int n = SEQL * DP;
    for (int i = blockIdx.x * blockDim.x + threadIdx.x; i < n; i += gridDim.x * blockDim.x){
        int r = i / DP, c = i - r * DP;
        float v = (c < VECT) ? src[r * VECT + c] : 0.f;
        xf[i]  = v;
        cur[i] = f2bf(v);
    }
}

// ---------------- GEMM: Y[s][i][col] = sum_d A[s][i][d] * W[wsel][col][d] + bias[col]
// 256 thr = 4 waves; wave handles 16 rows; WG = 64 rows.
// OM: 1 = fp32 row-major; 3 = QKV fused: slices 0,1 bf16 row-major, slice 2 bf16 transposed.
template<int NT, int OM, bool WPERSEQ>
__global__ __launch_bounds__(256) void gemm_k(
    const u16* __restrict__ A, const u16* __restrict__ Wp,
    const float* __restrict__ b0, const float* __restrict__ b1, const float* __restrict__ b2,
    int nb, void* __restrict__ Out)
{
    const int lane = threadIdx.x & 63;
    const int wid  = threadIdx.x >> 6;
    const int s    = blockIdx.z;
    const int sl   = blockIdx.y;
    const int wsel = WPERSEQ ? s : sl;
    const int row0 = blockIdx.x * 64 + wid * 16;
    const int m    = lane & 15;
    const int q    = lane >> 4;

    const u16* Arow = A + ((long)s * SEQL + row0) * DP;
    const u16* W    = Wp + (long)wsel * (NT * 16) * DP;

    f32x4 zf = {0.f, 0.f, 0.f, 0.f};
    f32x4 acc[NT];
    #pragma unroll
    for (int n = 0; n < NT; n++) acc[n] = zf;

    for (int c = 0; c < DP / 32; ++c){
        const int koff = c * 32 + q * 8;
        bf16x8 a0 = *(const bf16x8*)(Arow + m * DP + koff);
        #pragma unroll
        for (int n = 0; n < NT; n++){
            bf16x8 b = *(const bf16x8*)(W + (n * 16 + m) * DP + koff);
            acc[n] = MFMA(a0, b, acc[n]);
        }
    }

    const int bsel = WPERSEQ ? s : sl;
    const float* bp = (bsel == 0) ? b0 : ((bsel == 1) ? b1 : b2);
    const long SLC = 2L * SEQL * DP;  // per-slice stride in QKV buffer

    #pragma unroll
    for (int n = 0; n < NT; n++){
        int col = n * 16 + m;
        float bv = (col < nb) ? bp[col] : 0.f;
        #pragma unroll
        for (int r = 0; r < 4; r++){
            long row = row0 + q * 4 + r;
            float v = acc[n][r] + bv;
            if (OM == 1){
                long off = ((long)s * SEQL + row) * (long)(NT * 16) + col;
                ((float*)Out)[off] = v;
            } else {  // OM == 3
                long off;
                if (sl < 2) off = ((long)(sl * 2 + s) * SEQL + row) * DP + col;
                else        off = 2 * SLC + ((long)s * DP + col) * SEQL + row;
                ((u16*)Out)[off] = f2bf(v);
            }
        }
    }
}

// ---------------- flash attention chunk: Onum = exp(QK^T*scale - 16) V (unnormalized),
// Lp = row sums. Linear grid 512 = 64 xi * 8 combos; combo = bid&7 -> (jc,s) so that
// round-robin XCD dispatch puts all WGs sharing one K/VT chunk on one XCD (L2 reuse).
__global__ __launch_bounds__(256) void flash_k(
    const u16* __restrict__ Q, const u16* __restrict__ K, const u16* __restrict__ VT,
    u16* __restrict__ Onum, float* __restrict__ Lp)
{
    const int lane = threadIdx.x & 63;
    const int wid  = threadIdx.x >> 6;
    const int bid  = blockIdx.x;
    const int s    = bid & 1;
    const int jc   = (bid >> 1) & 3;
    const int xi   = bid >> 3;
    const int row0 = xi * 64 + wid * 16;
    const int m = lane & 15, q = lane >> 4;

    __shared__ __align__(16) u16 pbuf_all[4][16 * 72];
    u16* pbuf = pbuf_all[wid];

    const u16* Qb  = Q  + ((long)s * SEQL + row0) * DP;
    const u16* Kb  = K  + (long)s * SEQL * DP;
    const u16* VTb = VT + (long)s * DP * SEQL;

    bf16x8 qf[10];
    #pragma unroll
    for (int c = 0; c < 10; c++)
        qf[c] = *(const bf16x8*)(Qb + m * DP + c * 32 + q * 8);

    f32x4 zf = {0.f, 0.f, 0.f, 0.f};
    f32x4 oacc[NQT];
    #pragma unroll
    for (int n = 0; n < NQT; n++) oacc[n] = zf;
    float lacc[4] = {0.f, 0.f, 0.f, 0.f};

    const float K2 = 0.057735026918962576f * L2E;  // scale * log2(e)
    const float MB = -16.f * L2E;                   // fixed max offset (scores bounded ~|4|)

    for (int j = jc * 32; j < jc * 32 + 32; ++j){
        f32x4 sA = zf, sB = zf;
        #pragma unroll
        for (int c = 0; c < 10; c++){
            const int koff = c * 32 + q * 8;
            bf16x8 kA = *(const bf16x8*)(Kb + (long)(j * 32 +      m) * DP + koff);
            bf16x8 kB = *(const bf16x8*)(Kb + (long)(j * 32 + 16 + m) * DP + koff);
            sA = MFMA(qf[c], kA, sA);
            sB = MFMA(qf[c], kB, sB);
        }
        #pragma unroll
        for (int r = 0; r < 4; r++){
            float a = __builtin_amdgcn_exp2f(fmaf(sA[r], K2, MB));
            float b = __builtin_amdgcn_exp2f(fmaf(sB[r], K2, MB));
            lacc[r] += a + b;
            pbuf[(q * 4 + r) * 72 +      m] = f2bf(a);
            pbuf[(q * 4 + r) * 72 + 16 + m] = f2bf(b);
        }
        asm volatile("s_waitcnt lgkmcnt(0)" ::: "memory");
        bf16x8 pf = *(const bf16x8*)(pbuf + m * 72 + q * 8);

        #pragma unroll
        for (int n = 0; n < NQT; n++){
            bf16x8 vb = *(const bf16x8*)(VTb + (long)(n * 16 + m) * SEQL + j * 32 + q * 8);
            oacc[n] = MFMA(pf, vb, oacc[n]);
        }
    }

    // reduce l over the 16 m-lanes (columns)
    #pragma unroll
    for (int r = 0; r < 4; r++){
        float t = lacc[r];
        t += __shfl_xor(t, 1); t += __shfl_xor(t, 2);
        t += __shfl_xor(t, 4); t += __shfl_xor(t, 8);
        lacc[r] = t;
    }
    const long grow0 = (long)s * SEQL + row0;   // global row base (0..2S)
    if (m == 0){
        #pragma unroll
        for (int r = 0; r < 4; r++)
            Lp[(long)jc * 2 * SEQL + grow0 + q * 4 + r] = lacc[r];
    }
    u16* Ob = Onum + ((long)jc * 2 * SEQL + grow0) * DP;
    #pragma unroll
    for (int n = 0; n < NQT; n++)
        #pragma unroll
        for (int r = 0; r < 4; r++)
            Ob[(long)(q * 4 + r) * DP + n * 16 + m] = f2bf(oacc[n][r]);
}

// ---------------- combine chunks + LayerNorm1: out = LN(sum(Onum)/sum(l) + XF) * g + b
__global__ __launch_bounds__(256) void lncomb_k(const u16* __restrict__ Onum, const float* __restrict__ Lp,
                                                const float* __restrict__ XF,
                                                const float* __restrict__ g, const float* __restrict__ b,
                                                u16* __restrict__ OutB)
{
    long row = (long)((blockIdx.x * blockDim.x + threadIdx.x) >> 6);
    int lane = threadIdx.x & 63;
    if (row >= 2L * SEQL) return;
    float l = 0.f;
    #pragma unroll
    for (int jc = 0; jc < JC; jc++) l += Lp[(long)jc * 2 * SEQL + row];
    float inv = 1.f / l;
    const float* xr = XF + row * DP;
    float v[5], sum = 0.f, sq = 0.f;
    #pragma unroll
    for (int i = 0; i < 5; i++){
        int c = lane + i * 64;
        float o = 0.f;
        #pragma unroll
        for (int jc = 0; jc < JC; jc++)
            o += bf2f(Onum[((long)jc * 2 * SEQL + row) * DP + c]);
        float t = (c < VECT) ? (o * inv + xr[c]) : 0.f;
        v[i] = t; sum += t; sq += t * t;
    }
    #pragma unroll
    for (int o = 1; o < 64; o <<= 1){ sum += __shfl_xor(sum, o); sq += __shfl_xor(sq, o); }
    float mean = sum / VECT;
    float var  = sq / VECT - mean * mean;
    float rstd = rsqrtf(var + 1e-5f);
    #pragma unroll
    for (int i = 0; i < 5; i++){
        int c = lane + i * 64;
        float t = (c < VECT) ? ((v[i] - mean) * rstd * g[c] + b[c]) : 0.f;
        OutB[row * DP + c] = f2bf(t);
    }
}

// ---------------- LayerNorm2: out = LN(Xf + Res) * g + b ; OutB bf16 + OutF fp32
__global__ __launch_bounds__(256) void ln_k(const float* __restrict__ Xf,
                                            const float* __restrict__ Res0, const float* __restrict__ Res1,
                                            int rstride,
                                            const float* __restrict__ g, const float* __restrict__ b,
                                            u16* __restrict__ OutB, float* __restrict__ OutF)
{
    long row = (long)((blockIdx.x * blockDim.x + threadIdx.x) >> 6);
    int lane = threadIdx.x & 63;
    if (row >= 2L * SEQL) return;
    const float* xr = Xf + row * DP;
    const float* rr = (row < SEQL) ? (Res0 + row * (long)rstride)
                                   : (Res1 + (row - SEQL) * (long)rstride);
    float v[5], sum = 0.f, sq = 0.f;
    #pragma unroll
    for (int i = 0; i < 5; i++){
        int c = lane + i * 64;
        float t = (c < VECT) ? (xr[c] + rr[c]) : 0.f;
        v[i] = t; sum += t; sq += t * t;
    }
    #pragma unroll
    for (int o = 1; o < 64; o <<= 1){ sum += __shfl_xor(sum, o); sq += __shfl_xor(sq, o); }
    float mean = sum / VECT;
    float var  = sq / VECT - mean * mean;
    float rstd = rsqrtf(var + 1e-5f);
    #pragma unroll
    for (int i = 0; i < 5; i++){
        int c = lane + i * 64;
        float t = (c < VECT) ? ((v[i] - mean) * rstd * g[c] + b[c]) : 0.f;
        OutB[row * DP + c] = f2bf(t);
        if (OutF) OutF[row * DP + c] = t;
    }
}

// ---------------- GRU: sequential scan, 1 WG per sequence, 4 waves, 1 barrier/step.
// gx staged via LDS in 16-step double-buffered windows (HBM latency off critical path);
// MFMA accumulation depth 2 (two accs per t6) to halve dependent-MFMA serialization.
__global__ __launch_bounds__(256) void gru_k(
    const float* __restrict__ GX,                          // [2][SEQL][384] fp32
    const u16* __restrict__ WhhB,                          // [2][384][128] bf16
    const float* __restrict__ Bhh1, const float* __restrict__ Bhh2,
    float* __restrict__ Hout)                              // [2][128] fp32
{
    const int s = blockIdx.x;
    const int lane = threadIdx.x & 63;
    const int wid  = threadIdx.x >> 6;
    const int td   = threadIdx.x;
    const int m = lane & 15, q = lane >> 4;
    const u16* Whh = WhhB + (long)s * G3 * HN;
    const float* Bhh = s ? Bhh2 : Bhh1;
    const float* gx = GX + (long)s * SEQL * G3;

    __shared__ __align__(16) float gxs[2][16 * G3];   // 48 KB gx staging (16-step windows)
    __shared__ __align__(16) float ghb[2][G3];

    bf16x8 af[6][4];
    #pragma unroll
    for (int t6 = 0; t6 < 6; t6++)
        #pragma unroll
        for (int c = 0; c < 4; c++)
            af[t6][c] = *(const bf16x8*)(Whh + (wid * 96 + t6 * 16 + m) * HN + c * 32 + q * 8);

    const int i0 = 2 * lane, i1 = i0 + 1;
    const float bhr0 = Bhh[i0],        bhr1 = Bhh[i1];
    const float bhz0 = Bhh[HN + i0],   bhz1 = Bhh[HN + i1];
    const float bhn0 = Bhh[2*HN + i0], bhn1 = Bhh[2*HN + i1];

    // ---- prologue: stage window 0 to LDS; window 1 pending in regs
    float2 st[12];
    #pragma unroll
    for (int k = 0; k < 12; k++) st[k] = *(const float2*)(gx + k * 512 + td * 2);
    #pragma unroll
    for (int k = 0; k < 12; k++) *(float2*)(&gxs[0][k * 512 + td * 2]) = st[k];
    #pragma unroll
    for (int k = 0; k < 12; k++) st[k] = *(const float2*)(gx + 6144 + k * 512 + td * 2);
    asm volatile("s_waitcnt lgkmcnt(0)" ::: "memory");
    __builtin_amdgcn_s_barrier();
    asm volatile("" ::: "memory");

    float2 cr = *(const float2*)(&gxs[0][i0]);
    float2 cz = *(const float2*)(&gxs[0][HN + i0]);
    float2 cn = *(const float2*)(&gxs[0][2*HN + i0]);

    float h0 = 0.f, h1 = 0.f;
    unsigned hpk = 0;
    const f32x4 zf = {0.f, 0.f, 0.f, 0.f};

    for (int t = 0; t < SEQL; t++){
        // B-frags: replicate h into all 16 columns (pairs via bpermute)
        bf16x8 bf_[4];
        #pragma unroll
        for (int c = 0; c < 4; c++){
            union { unsigned u[4]; bf16x8 v; } bu;
            #pragma unroll
            for (int jj = 0; jj < 4; jj++)
                bu.u[jj] = (unsigned)__builtin_amdgcn_ds_bpermute((c * 16 + q * 4 + jj) * 4, (int)hpk);
            bf_[c] = bu.v;
        }
        // matvec: 6 row-tiles, accumulation depth 2
        #pragma unroll
        for (int t6 = 0; t6 < 6; t6++){
            f32x4 a0 = zf, a1 = zf;
            a0 = MFMA(af[t6][0], bf_[0], a0);
            a1 = MFMA(af[t6][2], bf_[2], a1);
            a0 = MFMA(af[t6][1], bf_[1], a0);
            a1 = MFMA(af[t6][3], bf_[3], a1);
            if (m == 0)
                *(f32x4*)(&ghb[t & 1][wid * 96 + t6 * 16 + q * 4]) = a0 + a1;
        }
        // window boundary: flush pending regs -> LDS (next window), issue loads for window+1
        if ((t & 15) == 15 && t + 1 < SEQL){
            int wb = (t + 1) >> 4;
            float* db = &gxs[wb & 1][0];
            #pragma unroll
            for (int k = 0; k < 12; k++) *(float2*)(&db[k * 512 + td * 2]) = st[k];
            int wn = wb + 1; if (wn > (SEQL / 16) - 1) wn = (SEQL / 16) - 1;
            const float* gs = gx + (long)wn * 6144;
            #pragma unroll
            for (int k = 0; k < 12; k++) st[k] = *(const float2*)(gs + k * 512 + td * 2);
        }
        // raw barrier: LDS drain only; staged global loads stay in flight
        asm volatile("s_waitcnt lgkmcnt(0)" ::: "memory");
        __builtin_amdgcn_s_barrier();
        asm volatile("" ::: "memory");

        const float* gb = ghb[t & 1];
        float2 ghr = *(const float2*)(gb + i0);
        float2 ghz = *(const float2*)(gb + HN + i0);
        float2 ghn = *(const float2*)(gb + 2*HN + i0);

        float r0 = sigm_f(cr.x + ghr.x + bhr0);
        float r1 = sigm_f(cr.y + ghr.y + bhr1);
        float z0 = sigm_f(cz.x + ghz.x + bhz0);
        float z1 = sigm_f(cz.y + ghz.y + bhz1);
        float n0 = tanh_f(cn.x + r0 * (ghn.x + bhn0));
        float n1 = tanh_f(cn.y + r1 * (ghn.y + bhn1));
        h0 = (1.f - z0) * n0 + z0 * h0;
        h1 = (1.f - z1) * n1 + z1 * h1;
        hpk = ((unsigned)f2bf(h1) << 16) | (unsigned)f2bf(h0);

        // gx for t+1 from LDS (visible: written >=1 barrier ago)
        int tn = t + 1;
        const float* gxb = &gxs[(tn >> 4) & 1][(tn & 15) * G3];
        cr = *(const float2*)(gxb + i0);
        cz = *(const float2*)(gxb + HN + i0);
        cn = *(const float2*)(gxb + 2*HN + i0);
    }
    if (wid == 0){
        Hout[s * HN + i0] = h0;
        Hout[s * HN + i1] = h1;
    }
}

// ---------------- head: fc1+relu, fc2, log_softmax -> 3 fp32
__global__ __launch_bounds__(256) void final_k(const float* __restrict__ Hout,
                                               const float* __restrict__ fc1w, const float* __restrict__ fc1b,
                                               const float* __restrict__ fc2w, const float* __restrict__ fc2b,
                                               float* __restrict__ out)
{
    __shared__ float hb[256];
    __shared__ float r1[256];
    __shared__ float lg[3];
    int tid = threadIdx.x;
    hb[tid] = Hout[tid];
    __syncthreads();
    float a = 0.f;
    for (int k2 = 0; k2 < 256; k2++) a += hb[k2] * fc1w[tid * 256 + k2];
    a += fc1b[tid];
    r1[tid] = fmaxf(a, 0.f);
    __syncthreads();
    if (tid < 3){
        float v = 0.f;
        for (int k2 = 0; k2 < 256; k2++) v += r1[k2] * fc2w[tid * 256 + k2];
        lg[tid] = v + fc2b[tid];
    }
    __syncthreads();
    if (tid == 0){
        float mx = fmaxf(lg[0], fmaxf(lg[1], lg[2]));
        float se = __expf(lg[0] - mx) + __expf(lg[1] - mx) + __expf(lg[2] - mx);
        float ls = mx + logf(se);
        out[0] = lg[0] - ls;
        out[1] = lg[1] - ls;
        out[2] = lg[2] - ls;
    }
}

extern "C" void kernel_launch(void* const* d_in, const int* in_sizes, int n_in,
                              void* d_out, int out_size, void* d_ws, size_t ws_size,
                              hipStream_t stream)
{
    (void)in_sizes; (void)n_in; (void)out_size; (void)ws_size;
    const float* x1     = (const float*)d_in[0];
    const float* x2     = (const float*)d_in[1];
    const float* q_w    = (const float*)d_in[2],  *q_b   = (const float*)d_in[3];
    const float* k_w    = (const float*)d_in[4],  *k_b   = (const float*)d_in[5];
    const float* v_w    = (const float*)d_in[6],  *v_b   = (const float*)d_in[7];
    const float* aln_g  = (const float*)d_in[8],  *aln_b = (const float*)d_in[9];
    const float* w_w    = (const float*)d_in[10], *w_b   = (const float*)d_in[11];
    const float* mln_g  = (const float*)d_in[12], *mln_b = (const float*)d_in[13];
    const float* g1_wih = (const float*)d_in[14], *g1_whh = (const float*)d_in[15];
    const float* g1_bih = (const float*)d_in[16], *g1_bhh = (const float*)d_in[17];
    const float* g2_wih = (const float*)d_in[18], *g2_whh = (const float*)d_in[19];
    const float* g2_bih = (const float*)d_in[20], *g2_bhh = (const float*)d_in[21];
    const float* fc1w   = (const float*)d_in[22], *fc1b  = (const float*)d_in[23];
    const float* fc2w   = (const float*)d_in[24], *fc2b  = (const float*)d_in[25];

    char* wsp = (char*)d_ws;
    auto alloc = [&](size_t bytes) -> char* {
        char* p = wsp; wsp += (bytes + 255) & ~(size_t)255; return p;
    };
    float* XF   = (float*)alloc(2L * SEQL * DP * 4);   // fp32 stack input (residual for aln)
    u16*   CUR  = (u16*)  alloc(2L * SEQL * DP * 2);   // bf16 stack input (MFMA operand)
    u16*   Hb   = (u16*)  alloc(2L * SEQL * DP * 2);   // LN1 output bf16
    u16*   Wpk  = (u16*)  alloc(4L * DP * DP * 2);     // q,k,v,w packed bf16 [320][320]
    u16*   GWpk = (u16*)  alloc(2L * G3 * DP * 2);     // g{1,2}_wih packed bf16 [384][320]
    u16*   WhhB = (u16*)  alloc(2L * G3 * HN * 2);     // g{1,2}_whh bf16 [384][128]
    float* qbS  = (float*)alloc(DP * 4);               // q bias copy
    float* Hout = (float*)alloc(2L * HN * 4);
    float* Lp   = (float*)alloc((long)JC * 2 * SEQL * 4);
    // union1: {QK 2 slices + VT} vs GX
    size_t u1 = (2L * 2 * SEQL * DP + 2L * DP * SEQL) * 2;
    size_t u1b = 2L * SEQL * G3 * 4;
    u16*   QKV  = (u16*)  alloc(u1 > u1b ? u1 : u1b);
    u16*   VT   = QKV + 2L * 2 * SEQL * DP;
    float* GX   = (float*)QKV;
    // union2: Opart (flash numerator partials, bf16) vs Of (fp32 W-proj out)
    size_t u2 = (long)JC * 2 * SEQL * DP * 2;
    size_t u2b = 2L * SEQL * DP * 4;
    u16*   Onum = (u16*)  alloc(u2 > u2b ? u2 : u2b);
    float* Of   = (float*)Onum;

    // prep
    pad_x<<<256, 256, 0, stream>>>(x1, XF,                  CUR);
    pad_x<<<256, 256, 0, stream>>>(x2, XF + (long)SEQL*DP,  CUR + (long)SEQL*DP);
    cvt_pad<<<128, 256, 0, stream>>>(q_w, Wpk,                VECT, VECT, DP, DP, 1.f);
    cvt_pad<<<128, 256, 0, stream>>>(k_w, Wpk + 1L * DP * DP, VECT, VECT, DP, DP, 1.f);
    cvt_pad<<<128, 256, 0, stream>>>(v_w, Wpk + 2L * DP * DP, VECT, VECT, DP, DP, 1.f);
    cvt_pad<<<128, 256, 0, stream>>>(w_w, Wpk + 3L * DP * DP, VECT, VECT, DP, DP, 1.f);
    cvt_pad<<<128, 256, 0, stream>>>(g1_wih, GWpk,                 G3, VECT, G3, DP, 1.f);
    cvt_pad<<<128, 256, 0, stream>>>(g2_wih, GWpk + (long)G3 * DP, G3, VECT, G3, DP, 1.f);
    cvt_pad<<<64, 256, 0, stream>>>(g1_whh, WhhB,                 G3, HN, G3, HN, 1.f);
    cvt_pad<<<64, 256, 0, stream>>>(g2_whh, WhhB + (long)G3 * HN, G3, HN, G3, HN, 1.f);
    scale_copy<<<2, 256, 0, stream>>>(q_b, qbS, VECT, 1.f);

    for (int st = 0; st < 3; ++st){
        // Q,K -> QKV slices 0,1 ; V -> transposed at slice 2 (VT)
        gemm_k<NQT, 3, false><<<dim3(SEQL / 64, 3, 2), 256, 0, stream>>>(
            CUR, Wpk, qbS, k_b, v_b, VECT, QKV);
        flash_k<<<dim3((SEQL / 64) * JC * 2), 256, 0, stream>>>(QKV, QKV + 2L*SEQL*DP, VT, Onum, Lp);
        lncomb_k<<<dim3(2 * SEQL / 4), 256, 0, stream>>>(Onum, Lp, XF, aln_g, aln_b, Hb);
        gemm_k<NQT, 1, false><<<dim3(SEQL / 64, 1, 2), 256, 0, stream>>>(
            Hb, Wpk + 3L * DP * DP, w_b, nullptr, nullptr, VECT, Of);
        ln_k<<<dim3(2 * SEQL / 4), 256, 0, stream>>>(Of, x1, x2, VECT, mln_g, mln_b, CUR, XF);
    }

    // GRU input projections (weight/bias per seq) -> GX (aliases QKV, now dead)
    gemm_k<24, 1, true><<<dim3(SEQL / 64, 1, 2), 256, 0, stream>>>(
        CUR, GWpk, g1_bih, g2_bih, nullptr, G3, GX);
    gru_k<<<dim3(2), 256, 0, stream>>>(GX, WhhB, g1_bhh, g2_bhh, Hout);
    final_k<<<dim3(1), 256, 0, stream>>>(Hout, fc1w, fc1b, fc2w, fc2b, (float*)d_out);
}

// Round 6
// 3820.994 us; speedup vs baseline: 1.2954x; 1.2954x over previous
//
#include <hip/hip_runtime.h>
#include <hip/hip_bf16.h>

// Problem constants
#define SEQL 4096
#define VECT 300
#define DP   320     // padded feature dim (k-dim), 10 chunks of 32
#define NQT  20      // n-tiles (320 cols) for projection GEMMs
#define HN   128
#define G3   384     // 3*H
#define JC   4       // flash j-chunks (split-K over key dim)

typedef unsigned short u16;
typedef __attribute__((ext_vector_type(8))) short bf16x8;  // 8 bf16 = 4 VGPRs
typedef __attribute__((ext_vector_type(4))) float f32x4;

#define MFMA(a,b,c) __builtin_amdgcn_mfma_f32_16x16x32_bf16(a,b,c,0,0,0)
// Verified layouts (learn_hip m89/m91/m120):
//   A[m][k]: m=lane&15, k=(lane>>4)*8+j
//   B[k][n]: n=lane&15, k=(lane>>4)*8+j
//   C/D[row][col]: col=lane&15, row=(lane>>4)*4+reg

#define L2E 1.44269504088896f

__device__ __forceinline__ float bf2f(u16 v){
    union { unsigned u; float f; } t; t.u = ((unsigned)v) << 16; return t.f;
}
__device__ __forceinline__ u16 f2bf(float f){
    union { float f; unsigned u; } t; t.f = f;
    return (u16)((t.u + 0x7FFFu + ((t.u >> 16) & 1u)) >> 16);
}
__device__ __forceinline__ float sigm_f(float x){
    return __builtin_amdgcn_rcpf(1.f + __builtin_amdgcn_exp2f(-L2E * x));
}
__device__ __forceinline__ float tanh_f(float x){
    return fmaf(2.f, __builtin_amdgcn_rcpf(1.f + __builtin_amdgcn_exp2f(-2.f * L2E * x)), -1.f);
}

// ---------------- fp32 [R][C] -> bf16 padded [Rp][Cp], optional scale
__global__ __launch_bounds__(256) void cvt_pad(const float* __restrict__ src,
                                               u16* __restrict__ dst,
                                               int R, int C, int Rp, int Cp, float scale)
{
    int n = Rp * Cp;
    for (int i = blockIdx.x * blockDim.x + threadIdx.x; i < n; i += gridDim.x * blockDim.x){
        int r = i / Cp, c = i - r * Cp;
        float v = (r < R && c < C) ? src[r * C + c] * scale : 0.f;
        dst[i] = f2bf(v);
    }
}

// ---------------- fp32 vector scale-copy
__global__ __launch_bounds__(256) void scale_copy(const float* __restrict__ src,
                                                  float* __restrict__ dst, int n, float scale)
{
    int i = blockIdx.x * blockDim.x + threadIdx.x;
    if (i < n) dst[i] = src[i] * scale;
}

// ---------------- x: fp32 [S][300] -> XF fp32 [S][320] + CUR bf16 [S][320]
__global__ __launch_bounds__(256) void pad_x(const float* __restrict__ src,
                                             float* __restrict__ xf, u16* __restrict__ cur)
{
    int n = SEQL * DP;
    for (int i = blockIdx.x * blockDim.x + threadIdx.x; i < n; i += gridDim.x * blockDim.x){
        int r = i / DP, c = i - r * DP;
        float v = (c < VECT) ? src[r * VECT + c] : 0.f;
        xf[i]  = v;
        cur[i] = f2bf(v);
    }
}

// ---------------- GEMM: Y[s][i][col] = sum_d A[s][i][d] * W[wsel][col][d] + bias[col]
// 256 thr = 4 waves; wave handles 16 rows; WG = 64 rows.
// OM: 1 = fp32 row-major; 3 = QKV fused: slices 0,1 bf16 row-major, slice 2 bf16 transposed.
template<int NT, int OM, bool WPERSEQ>
__global__ __launch_bounds__(256) void gemm_k(
    const u16* __restrict__ A, const u16* __restrict__ Wp,
    const float* __restrict__ b0, const float* __restrict__ b1, const float* __restrict__ b2,
    int nb, void* __restrict__ Out)
{
    const int lane = threadIdx.x & 63;
    const int wid  = threadIdx.x >> 6;
    const int s    = blockIdx.z;
    const int sl   = blockIdx.y;
    const int wsel = WPERSEQ ? s : sl;
    const int row0 = blockIdx.x * 64 + wid * 16;
    const int m    = lane & 15;
    const int q    = lane >> 4;

    const u16* Arow = A + ((long)s * SEQL + row0) * DP;
    const u16* W    = Wp + (long)wsel * (NT * 16) * DP;

    f32x4 zf = {0.f, 0.f, 0.f, 0.f};
    f32x4 acc[NT];
    #pragma unroll
    for (int n = 0; n < NT; n++) acc[n] = zf;

    for (int c = 0; c < DP / 32; ++c){
        const int koff = c * 32 + q * 8;
        bf16x8 a0 = *(const bf16x8*)(Arow + m * DP + koff);
        #pragma unroll
        for (int n = 0; n < NT; n++){
            bf16x8 b = *(const bf16x8*)(W + (n * 16 + m) * DP + koff);
            acc[n] = MFMA(a0, b, acc[n]);
        }
    }

    const int bsel = WPERSEQ ? s : sl;
    const float* bp = (bsel == 0) ? b0 : ((bsel == 1) ? b1 : b2);
    const long SLC = 2L * SEQL * DP;  // per-slice stride in QKV buffer

    #pragma unroll
    for (int n = 0; n < NT; n++){
        int col = n * 16 + m;
        float bv = (col < nb) ? bp[col] : 0.f;
        #pragma unroll
        for (int r = 0; r < 4; r++){
            long row = row0 + q * 4 + r;
            float v = acc[n][r] + bv;
            if (OM == 1){
                long off = ((long)s * SEQL + row) * (long)(NT * 16) + col;
                ((float*)Out)[off] = v;
            } else {  // OM == 3
                long off;
                if (sl < 2) off = ((long)(sl * 2 + s) * SEQL + row) * DP + col;
                else        off = 2 * SLC + ((long)s * DP + col) * SEQL + row;
                ((u16*)Out)[off] = f2bf(v);
            }
        }
    }
}

// ---------------- flash attention chunk: Onum = exp(QK^T*scale - 16) V (unnormalized),
// Lp = row sums. Linear grid 512 = 64 xi * 8 combos; combo = bid&7 -> (jc,s) so that
// round-robin XCD dispatch puts all WGs sharing one K/VT chunk on one XCD (L2 reuse).
__global__ __launch_bounds__(256) void flash_k(
    const u16* __restrict__ Q, const u16* __restrict__ K, const u16* __restrict__ VT,
    u16* __restrict__ Onum, float* __restrict__ Lp)
{
    const int lane = threadIdx.x & 63;
    const int wid  = threadIdx.x >> 6;
    const int bid  = blockIdx.x;
    const int s    = bid & 1;
    const int jc   = (bid >> 1) & 3;
    const int xi   = bid >> 3;
    const int row0 = xi * 64 + wid * 16;
    const int m = lane & 15, q = lane >> 4;

    __shared__ __align__(16) u16 pbuf_all[4][16 * 72];
    u16* pbuf = pbuf_all[wid];

    const u16* Qb  = Q  + ((long)s * SEQL + row0) * DP;
    const u16* Kb  = K  + (long)s * SEQL * DP;
    const u16* VTb = VT + (long)s * DP * SEQL;

    bf16x8 qf[10];
    #pragma unroll
    for (int c = 0; c < 10; c++)
        qf[c] = *(const bf16x8*)(Qb + m * DP + c * 32 + q * 8);

    f32x4 zf = {0.f, 0.f, 0.f, 0.f};
    f32x4 oacc[NQT];
    #pragma unroll
    for (int n = 0; n < NQT; n++) oacc[n] = zf;
    float lacc[4] = {0.f, 0.f, 0.f, 0.f};

    const float K2 = 0.057735026918962576f * L2E;  // scale * log2(e)
    const float MB = -16.f * L2E;                   // fixed max offset (scores bounded ~|4|)

    for (int j = jc * 32; j < jc * 32 + 32; ++j){
        f32x4 sA = zf, sB = zf;
        #pragma unroll
        for (int c = 0; c < 10; c++){
            const int koff = c * 32 + q * 8;
            bf16x8 kA = *(const bf16x8*)(Kb + (long)(j * 32 +      m) * DP + koff);
            bf16x8 kB = *(const bf16x8*)(Kb + (long)(j * 32 + 16 + m) * DP + koff);
            sA = MFMA(qf[c], kA, sA);
            sB = MFMA(qf[c], kB, sB);
        }
        #pragma unroll
        for (int r = 0; r < 4; r++){
            float a = __builtin_amdgcn_exp2f(fmaf(sA[r], K2, MB));
            float b = __builtin_amdgcn_exp2f(fmaf(sB[r], K2, MB));
            lacc[r] += a + b;
            pbuf[(q * 4 + r) * 72 +      m] = f2bf(a);
            pbuf[(q * 4 + r) * 72 + 16 + m] = f2bf(b);
        }
        asm volatile("s_waitcnt lgkmcnt(0)" ::: "memory");
        bf16x8 pf = *(const bf16x8*)(pbuf + m * 72 + q * 8);

        #pragma unroll
        for (int n = 0; n < NQT; n++){
            bf16x8 vb = *(const bf16x8*)(VTb + (long)(n * 16 + m) * SEQL + j * 32 + q * 8);
            oacc[n] = MFMA(pf, vb, oacc[n]);
        }
    }

    // reduce l over the 16 m-lanes (columns)
    #pragma unroll
    for (int r = 0; r < 4; r++){
        float t = lacc[r];
        t += __shfl_xor(t, 1); t += __shfl_xor(t, 2);
        t += __shfl_xor(t, 4); t += __shfl_xor(t, 8);
        lacc[r] = t;
    }
    const long grow0 = (long)s * SEQL + row0;   // global row base (0..2S)
    if (m == 0){
        #pragma unroll
        for (int r = 0; r < 4; r++)
            Lp[(long)jc * 2 * SEQL + grow0 + q * 4 + r] = lacc[r];
    }
    u16* Ob = Onum + ((long)jc * 2 * SEQL + grow0) * DP;
    #pragma unroll
    for (int n = 0; n < NQT; n++)
        #pragma unroll
        for (int r = 0; r < 4; r++)
            Ob[(long)(q * 4 + r) * DP + n * 16 + m] = f2bf(oacc[n][r]);
}

// ---------------- combine chunks + LayerNorm1: out = LN(sum(Onum)/sum(l) + XF) * g + b
__global__ __launch_bounds__(256) void lncomb_k(const u16* __restrict__ Onum, const float* __restrict__ Lp,
                                                const float* __restrict__ XF,
                                                const float* __restrict__ g, const float* __restrict__ b,
                                                u16* __restrict__ OutB)
{
    long row = (long)((blockIdx.x * blockDim.x + threadIdx.x) >> 6);
    int lane = threadIdx.x & 63;
    if (row >= 2L * SEQL) return;
    float l = 0.f;
    #pragma unroll
    for (int jc = 0; jc < JC; jc++) l += Lp[(long)jc * 2 * SEQL + row];
    float inv = 1.f / l;
    const float* xr = XF + row * DP;
    float v[5], sum = 0.f, sq = 0.f;
    #pragma unroll
    for (int i = 0; i < 5; i++){
        int c = lane + i * 64;
        float o = 0.f;
        #pragma unroll
        for (int jc = 0; jc < JC; jc++)
            o += bf2f(Onum[((long)jc * 2 * SEQL + row) * DP + c]);
        float t = (c < VECT) ? (o * inv + xr[c]) : 0.f;
        v[i] = t; sum += t; sq += t * t;
    }
    #pragma unroll
    for (int o = 1; o < 64; o <<= 1){ sum += __shfl_xor(sum, o); sq += __shfl_xor(sq, o); }
    float mean = sum / VECT;
    float var  = sq / VECT - mean * mean;
    float rstd = rsqrtf(var + 1e-5f);
    #pragma unroll
    for (int i = 0; i < 5; i++){
        int c = lane + i * 64;
        float t = (c < VECT) ? ((v[i] - mean) * rstd * g[c] + b[c]) : 0.f;
        OutB[row * DP + c] = f2bf(t);
    }
}

// ---------------- LayerNorm2: out = LN(Xf + Res) * g + b ; OutB bf16 + OutF fp32
__global__ __launch_bounds__(256) void ln_k(const float* __restrict__ Xf,
                                            const float* __restrict__ Res0, const float* __restrict__ Res1,
                                            int rstride,
                                            const float* __restrict__ g, const float* __restrict__ b,
                                            u16* __restrict__ OutB, float* __restrict__ OutF)
{
    long row = (long)((blockIdx.x * blockDim.x + threadIdx.x) >> 6);
    int lane = threadIdx.x & 63;
    if (row >= 2L * SEQL) return;
    const float* xr = Xf + row * DP;
    const float* rr = (row < SEQL) ? (Res0 + row * (long)rstride)
                                   : (Res1 + (row - SEQL) * (long)rstride);
    float v[5], sum = 0.f, sq = 0.f;
    #pragma unroll
    for (int i = 0; i < 5; i++){
        int c = lane + i * 64;
        float t = (c < VECT) ? (xr[c] + rr[c]) : 0.f;
        v[i] = t; sum += t; sq += t * t;
    }
    #pragma unroll
    for (int o = 1; o < 64; o <<= 1){ sum += __shfl_xor(sum, o); sq += __shfl_xor(sq, o); }
    float mean = sum / VECT;
    float var  = sq / VECT - mean * mean;
    float rstd = rsqrtf(var + 1e-5f);
    #pragma unroll
    for (int i = 0; i < 5; i++){
        int c = lane + i * 64;
        float t = (c < VECT) ? ((v[i] - mean) * rstd * g[c] + b[c]) : 0.f;
        OutB[row * DP + c] = f2bf(t);
        if (OutF) OutF[row * DP + c] = t;
    }
}

// ---------------- GRU: sequential scan, 1 WG per sequence, 4 waves, ONE raw barrier/step.
// Wave-private LDS h staging (1 write + 4 broadcast b128 reads, in-order within wave,
// no barrier); gh exchange double-buffered; gx via 1-step register prefetch issued at
// loop top (in flight across the whole step body).
__global__ __launch_bounds__(256, 1) void gru_k(
    const float* __restrict__ GX,                          // [2][SEQL][384] fp32
    const u16* __restrict__ WhhB,                          // [2][384][128] bf16
    const float* __restrict__ Bhh1, const float* __restrict__ Bhh2,
    float* __restrict__ Hout)                              // [2][128] fp32
{
    const int s = blockIdx.x;
    const int lane = threadIdx.x & 63;
    const int wid  = threadIdx.x >> 6;
    const int m = lane & 15, q = lane >> 4;
    const u16* Whh = WhhB + (long)s * G3 * HN;
    const float* Bhh = s ? Bhh2 : Bhh1;
    const float* gx = GX + (long)s * SEQL * G3;

    __shared__ __align__(16) u16   hstage[4][HN];   // per-wave private h copy (256 B each)
    __shared__ __align__(16) float ghb[2][G3];      // double-buffered gh exchange

    bf16x8 af[6][4];
    #pragma unroll
    for (int t6 = 0; t6 < 6; t6++)
        #pragma unroll
        for (int c = 0; c < 4; c++)
            af[t6][c] = *(const bf16x8*)(Whh + (wid * 96 + t6 * 16 + m) * HN + c * 32 + q * 8);

    const int i0 = 2 * lane, i1 = i0 + 1;
    const float bhr0 = Bhh[i0],        bhr1 = Bhh[i1];
    const float bhz0 = Bhh[HN + i0],   bhz1 = Bhh[HN + i1];
    const float bhn0 = Bhh[2*HN + i0], bhn1 = Bhh[2*HN + i1];

    // gx for t=0 (cur regs); per-iteration we prefetch t+1
    float2 cr = *(const float2*)(gx + i0);
    float2 cz = *(const float2*)(gx + HN + i0);
    float2 cn = *(const float2*)(gx + 2*HN + i0);

    float h0 = 0.f, h1 = 0.f;
    unsigned hpk = 0;
    const f32x4 zf = {0.f, 0.f, 0.f, 0.f};
    unsigned* hsw = (unsigned*)&hstage[wid][0];

    for (int t = 0; t < SEQL; t++){
        // 1. stage h_{t-1} into wave-private LDS (in-order LDS: no barrier needed)
        hsw[lane] = hpk;
        // 2. issue gx prefetch for t+1 (in flight across the whole step)
        int tn = (t + 1 < SEQL) ? t + 1 : t;
        const float* gp = gx + (long)tn * G3;
        float2 pr = *(const float2*)(gp + i0);
        float2 pz = *(const float2*)(gp + HN + i0);
        float2 pn = *(const float2*)(gp + 2*HN + i0);
        // 3. B-frags: broadcast reads (all 16 m-lanes same address)
        bf16x8 bf_[4];
        #pragma unroll
        for (int c = 0; c < 4; c++)
            bf_[c] = *(const bf16x8*)(&hstage[wid][c * 32 + q * 8]);
        // 4. matvec: 6 row-tiles x 4 k-chunks
        #pragma unroll
        for (int t6 = 0; t6 < 6; t6++){
            f32x4 a = zf;
            #pragma unroll
            for (int c = 0; c < 4; c++) a = MFMA(af[t6][c], bf_[c], a);
            if (m == 0)
                *(f32x4*)(&ghb[t & 1][wid * 96 + t6 * 16 + q * 4]) = a;
        }
        // 5. raw barrier: LDS drain only; gx global loads stay in flight
        asm volatile("s_waitcnt lgkmcnt(0)" ::: "memory");
        __builtin_amdgcn_s_barrier();
        asm volatile("" ::: "memory");
        // 6. gates
        const float* gb = ghb[t & 1];
        float2 ghr = *(const float2*)(gb + i0);
        float2 ghz = *(const float2*)(gb + HN + i0);
        float2 ghn = *(const float2*)(gb + 2*HN + i0);

        float r0 = sigm_f(cr.x + ghr.x + bhr0);
        float r1 = sigm_f(cr.y + ghr.y + bhr1);
        float z0 = sigm_f(cz.x + ghz.x + bhz0);
        float z1 = sigm_f(cz.y + ghz.y + bhz1);
        float n0 = tanh_f(cn.x + r0 * (ghn.x + bhn0));
        float n1 = tanh_f(cn.y + r1 * (ghn.y + bhn1));
        h0 = (1.f - z0) * n0 + z0 * h0;
        h1 = (1.f - z1) * n1 + z1 * h1;
        hpk = ((unsigned)f2bf(h1) << 16) | (unsigned)f2bf(h0);
        cr = pr; cz = pz; cn = pn;
    }
    if (wid == 0){
        Hout[s * HN + i0] = h0;
        Hout[s * HN + i1] = h1;
    }
}

// ---------------- head: fc1+relu, fc2, log_softmax -> 3 fp32
__global__ __launch_bounds__(256) void final_k(const float* __restrict__ Hout,
                                               const float* __restrict__ fc1w, const float* __restrict__ fc1b,
                                               const float* __restrict__ fc2w, const float* __restrict__ fc2b,
                                               float* __restrict__ out)
{
    __shared__ float hb[256];
    __shared__ float r1[256];
    __shared__ float lg[3];
    int tid = threadIdx.x;
    hb[tid] = Hout[tid];
    __syncthreads();
    float a = 0.f;
    for (int k2 = 0; k2 < 256; k2++) a += hb[k2] * fc1w[tid * 256 + k2];
    a += fc1b[tid];
    r1[tid] = fmaxf(a, 0.f);
    __syncthreads();
    if (tid < 3){
        float v = 0.f;
        for (int k2 = 0; k2 < 256; k2++) v += r1[k2] * fc2w[tid * 256 + k2];
        lg[tid] = v + fc2b[tid];
    }
    __syncthreads();
    if (tid == 0){
        float mx = fmaxf(lg[0], fmaxf(lg[1], lg[2]));
        float se = __expf(lg[0] - mx) + __expf(lg[1] - mx) + __expf(lg[2] - mx);
        float ls = mx + logf(se);
        out[0] = lg[0] - ls;
        out[1] = lg[1] - ls;
        out[2] = lg[2] - ls;
    }
}

extern "C" void kernel_launch(void* const* d_in, const int* in_sizes, int n_in,
                              void* d_out, int out_size, void* d_ws, size_t ws_size,
                              hipStream_t stream)
{
    (void)in_sizes; (void)n_in; (void)out_size; (void)ws_size;
    const float* x1     = (const float*)d_in[0];
    const float* x2     = (const float*)d_in[1];
    const float* q_w    = (const float*)d_in[2],  *q_b   = (const float*)d_in[3];
    const float* k_w    = (const float*)d_in[4],  *k_b   = (const float*)d_in[5];
    const float* v_w    = (const float*)d_in[6],  *v_b   = (const float*)d_in[7];
    const float* aln_g  = (const float*)d_in[8],  *aln_b = (const float*)d_in[9];
    const float* w_w    = (const float*)d_in[10], *w_b   = (const float*)d_in[11];
    const float* mln_g  = (const float*)d_in[12], *mln_b = (const float*)d_in[13];
    const float* g1_wih = (const float*)d_in[14], *g1_whh = (const float*)d_in[15];
    const float* g1_bih = (const float*)d_in[16], *g1_bhh = (const float*)d_in[17];
    const float* g2_wih = (const float*)d_in[18], *g2_whh = (const float*)d_in[19];
    const float* g2_bih = (const float*)d_in[20], *g2_bhh = (const float*)d_in[21];
    const float* fc1w   = (const float*)d_in[22], *fc1b  = (const float*)d_in[23];
    const float* fc2w   = (const float*)d_in[24], *fc2b  = (const float*)d_in[25];

    char* wsp = (char*)d_ws;
    auto alloc = [&](size_t bytes) -> char* {
        char* p = wsp; wsp += (bytes + 255) & ~(size_t)255; return p;
    };
    float* XF   = (float*)alloc(2L * SEQL * DP * 4);   // fp32 stack input (residual for aln)
    u16*   CUR  = (u16*)  alloc(2L * SEQL * DP * 2);   // bf16 stack input (MFMA operand)
    u16*   Hb   = (u16*)  alloc(2L * SEQL * DP * 2);   // LN1 output bf16
    u16*   Wpk  = (u16*)  alloc(4L * DP * DP * 2);     // q,k,v,w packed bf16 [320][320]
    u16*   GWpk = (u16*)  alloc(2L * G3 * DP * 2);     // g{1,2}_wih packed bf16 [384][320]
    u16*   WhhB = (u16*)  alloc(2L * G3 * HN * 2);     // g{1,2}_whh bf16 [384][128]
    float* qbS  = (float*)alloc(DP * 4);               // q bias copy
    float* Hout = (float*)alloc(2L * HN * 4);
    float* Lp   = (float*)alloc((long)JC * 2 * SEQL * 4);
    // union1: {QK 2 slices + VT} vs GX
    size_t u1 = (2L * 2 * SEQL * DP + 2L * DP * SEQL) * 2;
    size_t u1b = 2L * SEQL * G3 * 4;
    u16*   QKV  = (u16*)  alloc(u1 > u1b ? u1 : u1b);
    u16*   VT   = QKV + 2L * 2 * SEQL * DP;
    float* GX   = (float*)QKV;
    // union2: Opart (flash numerator partials, bf16) vs Of (fp32 W-proj out)
    size_t u2 = (long)JC * 2 * SEQL * DP * 2;
    size_t u2b = 2L * SEQL * DP * 4;
    u16*   Onum = (u16*)  alloc(u2 > u2b ? u2 : u2b);
    float* Of   = (float*)Onum;

    // prep
    pad_x<<<256, 256, 0, stream>>>(x1, XF,                  CUR);
    pad_x<<<256, 256, 0, stream>>>(x2, XF + (long)SEQL*DP,  CUR + (long)SEQL*DP);
    cvt_pad<<<128, 256, 0, stream>>>(q_w, Wpk,                VECT, VECT, DP, DP, 1.f);
    cvt_pad<<<128, 256, 0, stream>>>(k_w, Wpk + 1L * DP * DP, VECT, VECT, DP, DP, 1.f);
    cvt_pad<<<128, 256, 0, stream>>>(v_w, Wpk + 2L * DP * DP, VECT, VECT, DP, DP, 1.f);
    cvt_pad<<<128, 256, 0, stream>>>(w_w, Wpk + 3L * DP * DP, VECT, VECT, DP, DP, 1.f);
    cvt_pad<<<128, 256, 0, stream>>>(g1_wih, GWpk,                 G3, VECT, G3, DP, 1.f);
    cvt_pad<<<128, 256, 0, stream>>>(g2_wih, GWpk + (long)G3 * DP, G3, VECT, G3, DP, 1.f);
    cvt_pad<<<64, 256, 0, stream>>>(g1_whh, WhhB,                 G3, HN, G3, HN, 1.f);
    cvt_pad<<<64, 256, 0, stream>>>(g2_whh, WhhB + (long)G3 * HN, G3, HN, G3, HN, 1.f);
    scale_copy<<<2, 256, 0, stream>>>(q_b, qbS, VECT, 1.f);

    for (int st = 0; st < 3; ++st){
        // Q,K -> QKV slices 0,1 ; V -> transposed at slice 2 (VT)
        gemm_k<NQT, 3, false><<<dim3(SEQL / 64, 3, 2), 256, 0, stream>>>(
            CUR, Wpk, qbS, k_b, v_b, VECT, QKV);
        flash_k<<<dim3((SEQL / 64) * JC * 2), 256, 0, stream>>>(QKV, QKV + 2L*SEQL*DP, VT, Onum, Lp);
        lncomb_k<<<dim3(2 * SEQL / 4), 256, 0, stream>>>(Onum, Lp, XF, aln_g, aln_b, Hb);
        gemm_k<NQT, 1, false><<<dim3(SEQL / 64, 1, 2), 256, 0, stream>>>(
            Hb, Wpk + 3L * DP * DP, w_b, nullptr, nullptr, VECT, Of);
        ln_k<<<dim3(2 * SEQL / 4), 256, 0, stream>>>(Of, x1, x2, VECT, mln_g, mln_b, CUR, XF);
    }

    // GRU input projections (weight/bias per seq) -> GX (aliases QKV, now dead)
    gemm_k<24, 1, true><<<dim3(SEQL / 64, 1, 2), 256, 0, stream>>>(
        CUR, GWpk, g1_bih, g2_bih, nullptr, G3, GX);
    gru_k<<<dim3(2), 256, 0, stream>>>(GX, WhhB, g1_bhh, g2_bhh, Hout);
    final_k<<<dim3(1), 256, 0, stream>>>(Hout, fc1w, fc1b, fc2w, fc2b, (float*)d_out);
}